// Round 2
// baseline (455.491 us; speedup 1.0000x reference)
//
#include <hip/hip_runtime.h>
#include <cstdint>
#include <cstddef>

#define B_  8
#define S_  1024
#define K_  1024
#define H_  8
#define C_  32
#define AD_ 256
#define NT  16   // K tiles of 64

typedef __attribute__((ext_vector_type(4))) float f32x4;
typedef __attribute__((ext_vector_type(8))) short short8;
typedef __attribute__((ext_vector_type(4))) short short4v;

__device__ __forceinline__ short f2bf(float f) {
    union { float f; uint32_t u; } v; v.f = f;
    uint32_t r = (v.u + 0x7fffu + ((v.u >> 16) & 1u)) >> 16;  // RNE
    return (short)r;
}

#define MFMA16(a, b, c) __builtin_amdgcn_mfma_f32_16x16x32_bf16((a), (b), (c), 0, 0, 0)

// ---------------------------------------------------------------------------
// Kernel 0: transpose + cast weights f32 [a][hc] -> bf16 [w][hc][a]
// w order: 0=query_w, 1=gating_w, 2=key_w, 3=value_w
// ---------------------------------------------------------------------------
__global__ __launch_bounds__(256) void wprep_kernel(
    const float* __restrict__ qw, const float* __restrict__ gw,
    const float* __restrict__ kw, const float* __restrict__ vw,
    short* __restrict__ wt)
{
    __shared__ float tile[64][65];
    const int w  = blockIdx.x >> 4;
    const int ta = (blockIdx.x >> 2) & 3;
    const int th = blockIdx.x & 3;
    const float* src = (w == 0) ? qw : (w == 1) ? gw : (w == 2) ? kw : vw;
    const int tid = threadIdx.x;
    const int chunk = tid & 15, rr = tid >> 4;

    #pragma unroll
    for (int m = 0; m < 4; ++m) {
        int ra = m * 16 + rr;
        f32x4 v = *(const f32x4*)(src + (size_t)(ta * 64 + ra) * 256 + th * 64 + chunk * 4);
        #pragma unroll
        for (int j = 0; j < 4; ++j) tile[ra][chunk * 4 + j] = v[j];
    }
    __syncthreads();
    #pragma unroll
    for (int m = 0; m < 4; ++m) {
        int hc = m * 16 + rr;
        short4v o;
        #pragma unroll
        for (int j = 0; j < 4; ++j) o[j] = f2bf(tile[chunk * 4 + j][hc]);
        *(short4v*)(wt + (size_t)w * 65536 + (size_t)(th * 64 + hc) * 256 + ta * 64 + chunk * 4) = o;
    }
}

// ---------------------------------------------------------------------------
// Kernel 1: projections. grid (B*S/64, 2). y=0: q_data->{q,gate}; y=1: m_data->{k,vT}
// Each wave: 16 tokens x 512 outputs via MFMA 16x16x32 bf16.
// V is stored TRANSPOSED [b][h][c][k] so attn's PV B-fragments are contiguous.
// ---------------------------------------------------------------------------
__global__ __launch_bounds__(256) void proj_kernel(
    const float* __restrict__ qdata, const float* __restrict__ mdata,
    const float* __restrict__ qbias, const short* __restrict__ wt,
    short* __restrict__ qb, short* __restrict__ kb, short* __restrict__ vt,
    float* __restrict__ gate)
{
    const int y    = blockIdx.y;
    const int b    = blockIdx.x >> 4;
    const int tt   = blockIdx.x & 15;
    const int tid  = threadIdx.x;
    const int wave = tid >> 6, lane = tid & 63;
    const int row  = lane & 15, grp = lane >> 4;
    const int tok0 = tt * 64 + wave * 16;

    const float* X  = y ? mdata : qdata;
    const short* WT = wt + (y ? 2 * 65536 : 0);

    f32x4 acc[32];
    const f32x4 zz = {0.f, 0.f, 0.f, 0.f};
    #pragma unroll
    for (int n = 0; n < 32; ++n) acc[n] = zz;

    const float* xrow = X + (size_t)(b * S_ + tok0 + row) * AD_ + grp * 8;
    const short* wrow = WT + row * 256 + grp * 8;

    #pragma unroll
    for (int kc = 0; kc < 8; ++kc) {
        f32x4 x0 = *(const f32x4*)(xrow + kc * 32);
        f32x4 x1 = *(const f32x4*)(xrow + kc * 32 + 4);
        short8 af;
        #pragma unroll
        for (int j = 0; j < 4; ++j) { af[j] = f2bf(x0[j]); af[4 + j] = f2bf(x1[j]); }
        #pragma unroll
        for (int n = 0; n < 32; ++n) {
            short8 bf = *(const short8*)(wrow + n * 4096 + kc * 32);
            acc[n] = MFMA16(af, bf, acc[n]);
        }
    }

    const float scale_q = 0.17677669529663687f; // 32^-0.5
    #pragma unroll
    for (int n = 0; n < 32; ++n) {
        int colbase = (n & 15) * 16 + row;   // hc in [0,256)
        int h = colbase >> 5, c = colbase & 31;
        #pragma unroll
        for (int r = 0; r < 4; ++r) {
            int tok = tok0 + grp * 4 + r;    // C/D layout: row=(lane>>4)*4+r
            float v = acc[n][r];
            if (y == 0) {
                if (n < 16) {
                    float q = (v + qbias[colbase]) * scale_q;
                    qb[((size_t)(b * H_ + h) * S_ + tok) * C_ + c] = f2bf(q);
                } else {
                    float g = 1.f / (1.f + __expf(-v));
                    gate[((size_t)(b * S_ + tok) * H_ + h) * C_ + c] = g;
                }
            } else {
                if (n < 16) kb[((size_t)(b * H_ + h) * K_ + tok) * C_ + c] = f2bf(v);
                else        vt[((size_t)(b * H_ + h) * C_ + c) * K_ + tok] = f2bf(v);
            }
        }
    }
}

// ---------------------------------------------------------------------------
// Kernel 2: flash attention + gate. grid = 1024 blocks, 256 thr, NO barriers
// in the main loop. Wave w owns 16 q rows. K/V read straight from L2 (128KB
// per (b,h) — cache-resident; lesson: don't LDS-stage data that cache-fits).
// Bias (the 256MB stream) register-prefetched one tile ahead, folded into the
// QK^T MFMA C-operand. XCD-swizzled so all 16 q-tiles of one (b,h) share an
// XCD's L2 for K/V.
// ---------------------------------------------------------------------------
__global__ __launch_bounds__(256, 4) void attn_kernel(
    const short* __restrict__ qb, const short* __restrict__ kb,
    const short* __restrict__ vt, const float* __restrict__ gate,
    const float* __restrict__ bias, float* __restrict__ out)
{
    __shared__ short pbuf[4][16 * 72];   // per-wave P round-trip, pitch 72

    // XCD-aware decode: blocks with equal (b,h) land on the same XCD (%8).
    const int x   = blockIdx.x;
    const int xcd = x & 7;
    const int qt  = (x >> 3) & 15;
    const int gh  = (x >> 7) * 8 + xcd;  // 0..63
    const int b = gh >> 3, h = gh & 7;

    const int tid = threadIdx.x, wave = tid >> 6, lane = tid & 63;
    const int row = lane & 15, grp = lane >> 4;
    const int q0 = qt * 64 + wave * 16;

    const short* kb_bh = kb + (size_t)(b * H_ + h) * K_ * C_;   // [k][c]
    const short* vt_bh = vt + (size_t)(b * H_ + h) * C_ * K_;   // [c][k]

    // Q A-fragment: row = lane&15 (q row), k = grp*8+j (c dim, K=32 exactly)
    short8 qf = *(const short8*)(qb + ((size_t)(b * H_ + h) * S_ + q0 + row) * C_ + grp * 8);

    // bias fragment base: D-layout row = grp*4+r, col = t*16 + (lane&15)
    const float* bias_lane = bias + ((size_t)((b * H_ + h) * S_ + q0 + grp * 4)) * K_ + row;

    f32x4 bregv[4];
    #pragma unroll
    for (int t = 0; t < 4; ++t)
        #pragma unroll
        for (int r = 0; r < 4; ++r)
            bregv[t][r] = bias_lane[(size_t)r * K_ + t * 16];

    f32x4 acc0 = {0.f, 0.f, 0.f, 0.f}, acc1 = {0.f, 0.f, 0.f, 0.f};
    float m_r[4] = {-1e30f, -1e30f, -1e30f, -1e30f};
    float l_r[4] = {0.f, 0.f, 0.f, 0.f};

    for (int kt = 0; kt < NT; ++kt) {
        // 1. bias prefetch for next tile (the critical HBM stream)
        f32x4 bregn[4];
        if (kt + 1 < NT) {
            #pragma unroll
            for (int t = 0; t < 4; ++t)
                #pragma unroll
                for (int r = 0; r < 4; ++r)
                    bregn[t][r] = bias_lane[(size_t)r * K_ + (kt + 1) * 64 + t * 16];
        }
        // 2. QK^T: 4 MFMAs, K fragments straight from global (L2-hit, 1KB
        //    coalesced per load), bias pre-loaded as the C operand.
        f32x4 lg[4];
        #pragma unroll
        for (int t = 0; t < 4; ++t) {
            short8 kf = *(const short8*)(kb_bh + (size_t)(kt * 64 + t * 16 + row) * C_ + grp * 8);
            lg[t] = MFMA16(qf, kf, bregv[t]);
        }
        // 3. online softmax; exp fused with P store (rows in (grp,r), cols in (lane&15, t))
        #pragma unroll
        for (int r = 0; r < 4; ++r) {
            float tm = fmaxf(fmaxf(lg[0][r], lg[1][r]), fmaxf(lg[2][r], lg[3][r]));
            tm = fmaxf(tm, __shfl_xor(tm, 1));
            tm = fmaxf(tm, __shfl_xor(tm, 2));
            tm = fmaxf(tm, __shfl_xor(tm, 4));
            tm = fmaxf(tm, __shfl_xor(tm, 8));
            float mnew = fmaxf(m_r[r], tm);
            float sc = __expf(m_r[r] - mnew);
            float ps = 0.f;
            #pragma unroll
            for (int t = 0; t < 4; ++t) {
                float pv = __expf(lg[t][r] - mnew);
                ps += pv;
                pbuf[wave][(grp * 4 + r) * 72 + t * 16 + row] = f2bf(pv);
            }
            ps += __shfl_xor(ps, 1); ps += __shfl_xor(ps, 2);
            ps += __shfl_xor(ps, 4); ps += __shfl_xor(ps, 8);
            l_r[r] = l_r[r] * sc + ps;
            m_r[r] = mnew;
            acc0[r] *= sc;
            acc1[r] *= sc;
        }
        // per-wave LDS round-trip: DS pipe is in-order per wave; the waitcnt +
        // memory clobber stops compiler reordering (no cross-wave data here).
        asm volatile("s_waitcnt lgkmcnt(0)" ::: "memory");
        // 4. PV: P as A-fragment from LDS, V^T B-fragments straight from global
        #pragma unroll
        for (int half = 0; half < 2; ++half) {
            short8 pf = *(const short8*)&pbuf[wave][row * 72 + half * 32 + grp * 8];
            short8 v0 = *(const short8*)(vt_bh + (size_t)row * K_ + kt * 64 + half * 32 + grp * 8);
            short8 v1 = *(const short8*)(vt_bh + (size_t)(16 + row) * K_ + kt * 64 + half * 32 + grp * 8);
            acc0 = MFMA16(pf, v0, acc0);
            acc1 = MFMA16(pf, v1, acc1);
        }
        // 5. rotate bias prefetch
        if (kt + 1 < NT) {
            #pragma unroll
            for (int t = 0; t < 4; ++t) bregv[t] = bregn[t];
        }
    }

    // epilogue: normalize, gate, store f32 [b][s][h][vc]
    const float* gp = gate + ((size_t)(b * S_ + q0) * H_ + h) * C_;
    float* op = out + ((size_t)(b * S_ + q0) * H_ + h) * C_;
    #pragma unroll
    for (int r = 0; r < 4; ++r) {
        int tokr = grp * 4 + r;
        float inv = 1.f / l_r[r];
        size_t o = (size_t)tokr * H_ * C_;
        op[o + row]      = acc0[r] * inv * gp[o + row];
        op[o + 16 + row] = acc1[r] * inv * gp[o + 16 + row];
    }
}

// ---------------------------------------------------------------------------
extern "C" void kernel_launch(void* const* d_in, const int* in_sizes, int n_in,
                              void* d_out, int out_size, void* d_ws, size_t ws_size,
                              hipStream_t stream)
{
    (void)in_sizes; (void)n_in; (void)out_size; (void)ws_size;
    const float* q_data   = (const float*)d_in[0];
    const float* m_data   = (const float*)d_in[1];
    const float* bias     = (const float*)d_in[2];
    const float* query_w  = (const float*)d_in[3];
    const float* query_b  = (const float*)d_in[4];
    const float* key_w    = (const float*)d_in[5];
    const float* value_w  = (const float*)d_in[6];
    const float* gating_w = (const float*)d_in[7];
    float* out = (float*)d_out;

    char* ws = (char*)d_ws;
    short* qb   = (short*)(ws);                 // 4 MB bf16 [B][H][S][32]
    short* kb   = (short*)(ws + (4u << 20));    // 4 MB bf16 [B][H][K][32]
    short* vt   = (short*)(ws + (8u << 20));    // 4 MB bf16 [B][H][32][K]  (transposed V)
    float* gate = (float*)(ws + (12u << 20));   // 8 MB f32  [B][S][H][32]
    short* wt   = (short*)(ws + (20u << 20));   // 512 KB bf16 [4][256][256]

    wprep_kernel<<<64, 256, 0, stream>>>(query_w, gating_w, key_w, value_w, wt);
    proj_kernel<<<dim3(128, 2), 256, 0, stream>>>(q_data, m_data, query_b, wt,
                                                  qb, kb, vt, gate);
    attn_kernel<<<1024, 256, 0, stream>>>(qb, kb, vt, gate, bias, out);
}

// Round 3
// 444.751 us; speedup vs baseline: 1.0241x; 1.0241x over previous
//
#include <hip/hip_runtime.h>
#include <cstdint>
#include <cstddef>

#define B_  8
#define S_  1024
#define K_  1024
#define H_  8
#define C_  32
#define AD_ 256
#define NT  16   // K tiles of 64

typedef __attribute__((ext_vector_type(4))) float f32x4;
typedef __attribute__((ext_vector_type(8))) short short8;
typedef __attribute__((ext_vector_type(4))) short short4v;

__device__ __forceinline__ short f2bf(float f) {
    union { float f; uint32_t u; } v; v.f = f;
    uint32_t r = (v.u + 0x7fffu + ((v.u >> 16) & 1u)) >> 16;  // RNE
    return (short)r;
}

#define MFMA16(a, b, c) __builtin_amdgcn_mfma_f32_16x16x32_bf16((a), (b), (c), 0, 0, 0)

// ---------------------------------------------------------------------------
// Kernel 0: transpose + cast weights f32 [a][hc] -> bf16 [w][hc][a]
// w order: 0=query_w, 1=gating_w, 2=key_w, 3=value_w
// ---------------------------------------------------------------------------
__global__ __launch_bounds__(256) void wprep_kernel(
    const float* __restrict__ qw, const float* __restrict__ gw,
    const float* __restrict__ kw, const float* __restrict__ vw,
    short* __restrict__ wt)
{
    __shared__ float tile[64][65];
    const int w  = blockIdx.x >> 4;
    const int ta = (blockIdx.x >> 2) & 3;
    const int th = blockIdx.x & 3;
    const float* src = (w == 0) ? qw : (w == 1) ? gw : (w == 2) ? kw : vw;
    const int tid = threadIdx.x;
    const int chunk = tid & 15, rr = tid >> 4;

    #pragma unroll
    for (int m = 0; m < 4; ++m) {
        int ra = m * 16 + rr;
        f32x4 v = *(const f32x4*)(src + (size_t)(ta * 64 + ra) * 256 + th * 64 + chunk * 4);
        #pragma unroll
        for (int j = 0; j < 4; ++j) tile[ra][chunk * 4 + j] = v[j];
    }
    __syncthreads();
    #pragma unroll
    for (int m = 0; m < 4; ++m) {
        int hc = m * 16 + rr;
        short4v o;
        #pragma unroll
        for (int j = 0; j < 4; ++j) o[j] = f2bf(tile[chunk * 4 + j][hc]);
        *(short4v*)(wt + (size_t)w * 65536 + (size_t)(th * 64 + hc) * 256 + ta * 64 + chunk * 4) = o;
    }
}

// ---------------------------------------------------------------------------
// Kernel 1: projections, 4-way split to keep VGPRs spill-free.
// grid (B*S/64, 4). y: 0=q(+bias,scale), 1=gate(sigmoid), 2=k, 3=vT.
// Each wave: 16 tokens x 256 outputs via MFMA 16x16x32 bf16; acc[16]=64 VGPR
// (Round-2 version had acc[32]=128 VGPR + unrolled load cluster -> suspected
//  scratch spill; this is the single change under test this round.)
// V is stored TRANSPOSED [b][h][c][k] so attn's PV B-fragments are contiguous.
// ---------------------------------------------------------------------------
__global__ __launch_bounds__(256) void proj_kernel(
    const float* __restrict__ qdata, const float* __restrict__ mdata,
    const float* __restrict__ qbias, const short* __restrict__ wt,
    short* __restrict__ qb, short* __restrict__ kb, short* __restrict__ vt,
    float* __restrict__ gate)
{
    const int y    = blockIdx.y;          // 0=q 1=gate 2=k 3=vT
    const int b    = blockIdx.x >> 4;
    const int tt   = blockIdx.x & 15;
    const int tid  = threadIdx.x;
    const int wave = tid >> 6, lane = tid & 63;
    const int row  = lane & 15, grp = lane >> 4;
    const int tok0 = tt * 64 + wave * 16;

    const float* X  = (y < 2) ? qdata : mdata;
    const short* WT = wt + (size_t)y * 65536;   // wt order matches y order

    f32x4 acc[16];
    const f32x4 zz = {0.f, 0.f, 0.f, 0.f};
    #pragma unroll
    for (int n = 0; n < 16; ++n) acc[n] = zz;

    const float* xrow = X + (size_t)(b * S_ + tok0 + row) * AD_ + grp * 8;
    const short* wrow = WT + row * 256 + grp * 8;

    #pragma unroll
    for (int kc = 0; kc < 8; ++kc) {
        f32x4 x0 = *(const f32x4*)(xrow + kc * 32);
        f32x4 x1 = *(const f32x4*)(xrow + kc * 32 + 4);
        short8 af;
        #pragma unroll
        for (int j = 0; j < 4; ++j) { af[j] = f2bf(x0[j]); af[4 + j] = f2bf(x1[j]); }
        #pragma unroll
        for (int n = 0; n < 16; ++n) {
            short8 bf = *(const short8*)(wrow + n * 4096 + kc * 32);
            acc[n] = MFMA16(af, bf, acc[n]);
        }
    }

    const float scale_q = 0.17677669529663687f; // 32^-0.5
    #pragma unroll
    for (int n = 0; n < 16; ++n) {
        int colbase = n * 16 + row;          // hc in [0,256)
        int h = colbase >> 5, c = colbase & 31;
        #pragma unroll
        for (int r = 0; r < 4; ++r) {
            int tok = tok0 + grp * 4 + r;    // C/D layout: row=(lane>>4)*4+r
            float v = acc[n][r];
            if (y == 0) {
                float q = (v + qbias[colbase]) * scale_q;
                qb[((size_t)(b * H_ + h) * S_ + tok) * C_ + c] = f2bf(q);
            } else if (y == 1) {
                float g = 1.f / (1.f + __expf(-v));
                gate[((size_t)(b * S_ + tok) * H_ + h) * C_ + c] = g;
            } else if (y == 2) {
                kb[((size_t)(b * H_ + h) * K_ + tok) * C_ + c] = f2bf(v);
            } else {
                vt[((size_t)(b * H_ + h) * C_ + c) * K_ + tok] = f2bf(v);
            }
        }
    }
}

// ---------------------------------------------------------------------------
// Kernel 2: flash attention + gate. grid = 1024 blocks, 256 thr, NO barriers
// in the main loop. Wave w owns 16 q rows. K/V read straight from L2 (128KB
// per (b,h) — cache-resident; lesson: don't LDS-stage data that cache-fits).
// Bias (the 256MB stream) register-prefetched one tile ahead, folded into the
// QK^T MFMA C-operand. XCD-swizzled so all 16 q-tiles of one (b,h) share an
// XCD's L2 for K/V.  (UNCHANGED from Round 2 — isolating the proj fix.)
// ---------------------------------------------------------------------------
__global__ __launch_bounds__(256, 4) void attn_kernel(
    const short* __restrict__ qb, const short* __restrict__ kb,
    const short* __restrict__ vt, const float* __restrict__ gate,
    const float* __restrict__ bias, float* __restrict__ out)
{
    __shared__ short pbuf[4][16 * 72];   // per-wave P round-trip, pitch 72

    // XCD-aware decode: blocks with equal (b,h) land on the same XCD (%8).
    const int x   = blockIdx.x;
    const int xcd = x & 7;
    const int qt  = (x >> 3) & 15;
    const int gh  = (x >> 7) * 8 + xcd;  // 0..63
    const int b = gh >> 3, h = gh & 7;

    const int tid = threadIdx.x, wave = tid >> 6, lane = tid & 63;
    const int row = lane & 15, grp = lane >> 4;
    const int q0 = qt * 64 + wave * 16;

    const short* kb_bh = kb + (size_t)(b * H_ + h) * K_ * C_;   // [k][c]
    const short* vt_bh = vt + (size_t)(b * H_ + h) * C_ * K_;   // [c][k]

    // Q A-fragment: row = lane&15 (q row), k = grp*8+j (c dim, K=32 exactly)
    short8 qf = *(const short8*)(qb + ((size_t)(b * H_ + h) * S_ + q0 + row) * C_ + grp * 8);

    // bias fragment base: D-layout row = grp*4+r, col = t*16 + (lane&15)
    const float* bias_lane = bias + ((size_t)((b * H_ + h) * S_ + q0 + grp * 4)) * K_ + row;

    f32x4 bregv[4];
    #pragma unroll
    for (int t = 0; t < 4; ++t)
        #pragma unroll
        for (int r = 0; r < 4; ++r)
            bregv[t][r] = bias_lane[(size_t)r * K_ + t * 16];

    f32x4 acc0 = {0.f, 0.f, 0.f, 0.f}, acc1 = {0.f, 0.f, 0.f, 0.f};
    float m_r[4] = {-1e30f, -1e30f, -1e30f, -1e30f};
    float l_r[4] = {0.f, 0.f, 0.f, 0.f};

    for (int kt = 0; kt < NT; ++kt) {
        // 1. bias prefetch for next tile (the critical HBM stream)
        f32x4 bregn[4];
        if (kt + 1 < NT) {
            #pragma unroll
            for (int t = 0; t < 4; ++t)
                #pragma unroll
                for (int r = 0; r < 4; ++r)
                    bregn[t][r] = bias_lane[(size_t)r * K_ + (kt + 1) * 64 + t * 16];
        }
        // 2. QK^T: 4 MFMAs, K fragments straight from global (L2-hit, 1KB
        //    coalesced per load), bias pre-loaded as the C operand.
        f32x4 lg[4];
        #pragma unroll
        for (int t = 0; t < 4; ++t) {
            short8 kf = *(const short8*)(kb_bh + (size_t)(kt * 64 + t * 16 + row) * C_ + grp * 8);
            lg[t] = MFMA16(qf, kf, bregv[t]);
        }
        // 3. online softmax; exp fused with P store (rows in (grp,r), cols in (lane&15, t))
        #pragma unroll
        for (int r = 0; r < 4; ++r) {
            float tm = fmaxf(fmaxf(lg[0][r], lg[1][r]), fmaxf(lg[2][r], lg[3][r]));
            tm = fmaxf(tm, __shfl_xor(tm, 1));
            tm = fmaxf(tm, __shfl_xor(tm, 2));
            tm = fmaxf(tm, __shfl_xor(tm, 4));
            tm = fmaxf(tm, __shfl_xor(tm, 8));
            float mnew = fmaxf(m_r[r], tm);
            float sc = __expf(m_r[r] - mnew);
            float ps = 0.f;
            #pragma unroll
            for (int t = 0; t < 4; ++t) {
                float pv = __expf(lg[t][r] - mnew);
                ps += pv;
                pbuf[wave][(grp * 4 + r) * 72 + t * 16 + row] = f2bf(pv);
            }
            ps += __shfl_xor(ps, 1); ps += __shfl_xor(ps, 2);
            ps += __shfl_xor(ps, 4); ps += __shfl_xor(ps, 8);
            l_r[r] = l_r[r] * sc + ps;
            m_r[r] = mnew;
            acc0[r] *= sc;
            acc1[r] *= sc;
        }
        // per-wave LDS round-trip: DS pipe is in-order per wave; the waitcnt +
        // memory clobber stops compiler reordering (no cross-wave data here).
        asm volatile("s_waitcnt lgkmcnt(0)" ::: "memory");
        // 4. PV: P as A-fragment from LDS, V^T B-fragments straight from global
        #pragma unroll
        for (int half = 0; half < 2; ++half) {
            short8 pf = *(const short8*)&pbuf[wave][row * 72 + half * 32 + grp * 8];
            short8 v0 = *(const short8*)(vt_bh + (size_t)row * K_ + kt * 64 + half * 32 + grp * 8);
            short8 v1 = *(const short8*)(vt_bh + (size_t)(16 + row) * K_ + kt * 64 + half * 32 + grp * 8);
            acc0 = MFMA16(pf, v0, acc0);
            acc1 = MFMA16(pf, v1, acc1);
        }
        // 5. rotate bias prefetch
        if (kt + 1 < NT) {
            #pragma unroll
            for (int t = 0; t < 4; ++t) bregv[t] = bregn[t];
        }
    }

    // epilogue: normalize, gate, store f32 [b][s][h][vc]
    const float* gp = gate + ((size_t)(b * S_ + q0) * H_ + h) * C_;
    float* op = out + ((size_t)(b * S_ + q0) * H_ + h) * C_;
    #pragma unroll
    for (int r = 0; r < 4; ++r) {
        int tokr = grp * 4 + r;
        float inv = 1.f / l_r[r];
        size_t o = (size_t)tokr * H_ * C_;
        op[o + row]      = acc0[r] * inv * gp[o + row];
        op[o + 16 + row] = acc1[r] * inv * gp[o + 16 + row];
    }
}

// ---------------------------------------------------------------------------
extern "C" void kernel_launch(void* const* d_in, const int* in_sizes, int n_in,
                              void* d_out, int out_size, void* d_ws, size_t ws_size,
                              hipStream_t stream)
{
    (void)in_sizes; (void)n_in; (void)out_size; (void)ws_size;
    const float* q_data   = (const float*)d_in[0];
    const float* m_data   = (const float*)d_in[1];
    const float* bias     = (const float*)d_in[2];
    const float* query_w  = (const float*)d_in[3];
    const float* query_b  = (const float*)d_in[4];
    const float* key_w    = (const float*)d_in[5];
    const float* value_w  = (const float*)d_in[6];
    const float* gating_w = (const float*)d_in[7];
    float* out = (float*)d_out;

    char* ws = (char*)d_ws;
    short* qb   = (short*)(ws);                 // 4 MB bf16 [B][H][S][32]
    short* kb   = (short*)(ws + (4u << 20));    // 4 MB bf16 [B][H][K][32]
    short* vt   = (short*)(ws + (8u << 20));    // 4 MB bf16 [B][H][32][K]  (transposed V)
    float* gate = (float*)(ws + (12u << 20));   // 8 MB f32  [B][S][H][32]
    short* wt   = (short*)(ws + (20u << 20));   // 512 KB bf16 [4][256][256]

    wprep_kernel<<<64, 256, 0, stream>>>(query_w, gating_w, key_w, value_w, wt);
    proj_kernel<<<dim3(128, 4), 256, 0, stream>>>(q_data, m_data, query_b, wt,
                                                  qb, kb, vt, gate);
    attn_kernel<<<1024, 256, 0, stream>>>(qb, kb, vt, gate, bias, out);
}